// Round 3
// baseline (30.346 us; speedup 1.0000x reference)
//
#include <hip/hip_runtime.h>
#include <math.h>

// Biquad lowpass over [B, T] f32, T = 262144.
// Overlap-and-discard, LDS-staged coalesced I/O, occupancy-tuned:
//  - block of 256 threads owns a contiguous 4096-float segment (16/thread)
//  - stage [seg-48, seg+4096) via coalesced float4 loads into pad-swizzled
//    LDS (s(i) = i + (i>>4)): compute-phase address = 17*tid + const ->
//    banks (17*tid + c)%32, 17 coprime 32 -> 2-way across 64 lanes = free
//  - 48 warm-up + 16 output steps per thread (poles |z|~0.6425 ->
//    0.6425^48 ~ 6e-10 init-state error vs 2e-2 threshold)
//  - outputs in 16 registers (fully unrolled, static idx), staged back to
//    LDS, stored as coalesced float4 (no write amplification)
//  - LDS ~17.6 KB -> 8 blocks/CU (32 waves/CU) for phase overlap across
//    blocks; grid = 4096 blocks
constexpr int T_LEN = 262144;
constexpr int CH    = 16;              // outputs per thread
constexpr int WARM  = 48;              // multiple of 4 (float4 staging guard)
constexpr int TPB   = 256;
constexpr int SEG   = TPB * CH;        // 4096 floats per block
constexpr int LTOT  = SEG + WARM;      // 4144 floats staged
constexpr int LSWZ  = LTOT + LTOT/16 + 4; // 4407 words, ~17.6 KB
constexpr int BPR   = T_LEN / SEG;     // 64 blocks per row

__device__ __forceinline__ int swz(int i) { return i + (i >> 4); }

__global__ __launch_bounds__(TPB, 8) void lowpass_kernel(
    const float* __restrict__ x, float* __restrict__ out,
    float b0, float b1, float b2, float a1, float a2)
{
    __shared__ float lds[LSWZ];
    const int tid = threadIdx.x;
    const size_t rbase = (size_t)(blockIdx.x / BPR) * T_LEN;
    const int blk  = blockIdx.x % BPR;       // BPR=64 -> shifts
    const int seg0 = blk * SEG;              // row-local segment start
    const float* __restrict__ xr = x   + rbase;
    float*       __restrict__ yr = out + rbase;

    // ---- stage [seg0-WARM, seg0+SEG) coalesced; zeros before row start ----
    for (int m = tid; m < LTOT / 4; m += TPB) {
        const int idx  = 4 * m;              // local index in staged window
        const int gpos = seg0 - WARM + idx;  // row-local sample index
        float4 v = make_float4(0.f, 0.f, 0.f, 0.f);
        if (gpos >= 0) v = *reinterpret_cast<const float4*>(xr + gpos);
        const int sb = swz(idx);             // idx%16 in {0,4,8,12} -> 4 consec
        lds[sb + 0] = v.x; lds[sb + 1] = v.y;
        lds[sb + 2] = v.z; lds[sb + 3] = v.w;
    }
    __syncthreads();

    // ---- recurrence: 48 warm-up + 16 output steps ----
    // thread tid: local window [16*tid, 16*tid + 64); s(16*tid+t)=17*tid+t+(t>>4)
    float x1 = 0.f, x2 = 0.f, y1 = 0.f, y2 = 0.f;
    const int b = 17 * tid;
    float o[CH];
    #pragma unroll
    for (int t = 0; t < WARM; ++t) {
        const float xc = lds[b + t + (t >> 4)];          // compile-time offset
        const float u  = fmaf(b0, xc, fmaf(b1, x1, b2 * x2));
        const float y  = fmaf(-a1, y1, fmaf(-a2, y2, u));
        x2 = x1; x1 = xc; y2 = y1; y1 = y;
    }
    #pragma unroll
    for (int t = 0; t < CH; ++t) {
        // s(16*tid + 48 + t) = 17*tid + 51 + t   (t < 16)
        const float xc = lds[b + 51 + t];
        const float u  = fmaf(b0, xc, fmaf(b1, x1, b2 * x2));
        const float y  = fmaf(-a1, y1, fmaf(-a2, y2, u));
        x2 = x1; x1 = xc; y2 = y1; y1 = y;
        o[t] = fminf(fmaxf(y, -1.f), 1.f);
    }
    __syncthreads();   // all input reads done before overwrite

    // ---- stage outputs back (same swizzled slots as their input samples) ----
    #pragma unroll
    for (int t = 0; t < CH; ++t) lds[b + 51 + t] = o[t];
    __syncthreads();

    // ---- coalesced float4 store ----
    for (int m = tid; m < SEG / 4; m += TPB) {
        // local output index l = WARM + 4m; s(l) = 51 + 4m + (m>>2), 4 consec
        const int sb = 51 + 4 * m + (m >> 2);
        float4 v = make_float4(lds[sb], lds[sb + 1], lds[sb + 2], lds[sb + 3]);
        *reinterpret_cast<float4*>(yr + seg0 + 4 * m) = v;
    }
}

extern "C" void kernel_launch(void* const* d_in, const int* in_sizes, int n_in,
                              void* d_out, int out_size, void* d_ws, size_t ws_size,
                              hipStream_t stream) {
    const float* x = (const float*)d_in[0];
    float* out = (float*)d_out;
    const int rows = in_sizes[0] / T_LEN;    // 64

    // torchaudio lowpass_biquad coefficients (double -> f32, matches reference)
    const double SR = 22050.0, CUT = 0.4 * SR, Q = 0.707;
    double w0 = 2.0 * M_PI * CUT / SR;
    double alpha = sin(w0) / (2.0 * Q);
    double cosw = cos(w0);
    double a0d = 1.0 + alpha;
    float b0 = (float)((1.0 - cosw) / 2.0 / a0d);
    float b1 = (float)((1.0 - cosw) / a0d);
    float b2 = b0;
    float a1 = (float)(-2.0 * cosw / a0d);
    float a2 = (float)((1.0 - alpha) / a0d);

    const int blocks = rows * BPR;           // 64 * 64 = 4096
    lowpass_kernel<<<blocks, TPB, 0, stream>>>(x, out, b0, b1, b2, a1, a2);
}

// Round 4
// 28.097 us; speedup vs baseline: 1.0801x; 1.0801x over previous
//
#include <hip/hip_runtime.h>
#include <math.h>

// Biquad lowpass over [B, T] f32, T = 262144.
// Overlap-and-discard, all-b128 LDS pipeline:
//  - block of 256 threads owns a contiguous 4096-float segment (16/thread)
//  - XOR swizzle sw(i) = i ^ (((i>>4)&7)<<2) on word index: bijective,
//    keeps bits[1:0] -> every phase uses 16B-aligned float4 LDS ops.
//    * compute reads i=16*tid+4k: lanes 0-7 start banks {0,20,8,28,16,4,24,12}
//      -> each 8-lane group covers all 32 banks once: conflict-free b128
//    * staging/store i=4*lane+c: start banks all distinct: conflict-free b128
//  - 24 warm-up + 16 output steps per thread (poles |z|~0.6425 ->
//    0.6425^24 ~ 2.4e-5 init-state error vs 2e-2 threshold)
//  - outputs in regs (static unroll), staged via LDS, coalesced float4 store
constexpr int T_LEN = 262144;
constexpr int CH    = 16;              // outputs per thread
constexpr int WARM  = 24;              // multiple of 4
constexpr int TPB   = 256;
constexpr int SEG   = TPB * CH;        // 4096 floats per block
constexpr int LTOT  = SEG + WARM;      // 4120 floats staged
constexpr int LSWZ  = LTOT + 8;        // swizzle headroom (max sw < 4124)
constexpr int BPR   = T_LEN / SEG;     // 64 blocks per row

__device__ __forceinline__ int sw(int i) { return i ^ (((i >> 4) & 7) << 2); }

__global__ __launch_bounds__(TPB, 6) void lowpass_kernel(
    const float* __restrict__ x, float* __restrict__ out,
    float b0, float b1, float b2, float a1, float a2)
{
    __shared__ float lds[LSWZ];
    const int tid = threadIdx.x;
    const size_t rbase = (size_t)(blockIdx.x / BPR) * T_LEN;
    const int seg0 = (blockIdx.x % BPR) * SEG;   // row-local segment start
    const float* __restrict__ xr = x   + rbase;
    float*       __restrict__ yr = out + rbase;

    // ---- stage [seg0-WARM, seg0+SEG) as b128; zeros before row start ----
    #pragma unroll
    for (int j = 0; j < (LTOT / 4 + TPB - 1) / TPB; ++j) {   // 5 iters
        const int m = tid + j * TPB;
        if (m < LTOT / 4) {
            const int idx  = 4 * m;              // local staged index
            const int gpos = seg0 - WARM + idx;  // row-local sample index
            float4 v = make_float4(0.f, 0.f, 0.f, 0.f);
            if (gpos >= 0) v = *reinterpret_cast<const float4*>(xr + gpos);
            *reinterpret_cast<float4*>(&lds[sw(idx)]) = v;
        }
    }
    __syncthreads();

    // ---- recurrence: 24 warm-up + 16 output steps, b128 LDS reads ----
    // thread tid: local window [16*tid, 16*tid + 40); outputs at +24..+40
    float x1 = 0.f, x2 = 0.f, y1 = 0.f, y2 = 0.f;
    const int base = 16 * tid;

    auto step = [&](float xc) -> float {
        const float u = fmaf(b0, xc, fmaf(b1, x1, b2 * x2));
        const float y = fmaf(-a1, y1, fmaf(-a2, y2, u));
        x2 = x1; x1 = xc; y2 = y1; y1 = y;
        return y;
    };

    #pragma unroll
    for (int k = 0; k < WARM / 4; ++k) {         // 6 warm-up float4s
        float4 xv = *reinterpret_cast<const float4*>(&lds[sw(base + 4 * k)]);
        step(xv.x); step(xv.y); step(xv.z); step(xv.w);
    }
    float4 ov[CH / 4];                            // 4, static unroll only
    #pragma unroll
    for (int k = 0; k < CH / 4; ++k) {
        float4 xv = *reinterpret_cast<const float4*>(&lds[sw(base + WARM + 4 * k)]);
        ov[k].x = fminf(fmaxf(step(xv.x), -1.f), 1.f);
        ov[k].y = fminf(fmaxf(step(xv.y), -1.f), 1.f);
        ov[k].z = fminf(fmaxf(step(xv.z), -1.f), 1.f);
        ov[k].w = fminf(fmaxf(step(xv.w), -1.f), 1.f);
    }
    __syncthreads();   // all input reads done before overwrite

    // ---- stage outputs back (same swizzled slots as their inputs) ----
    #pragma unroll
    for (int k = 0; k < CH / 4; ++k)
        *reinterpret_cast<float4*>(&lds[sw(base + WARM + 4 * k)]) = ov[k];
    __syncthreads();

    // ---- coalesced float4 store ----
    #pragma unroll
    for (int j = 0; j < SEG / 4 / TPB; ++j) {    // 4 iters, exact
        const int m = tid + j * TPB;
        float4 v = *reinterpret_cast<const float4*>(&lds[sw(WARM + 4 * m)]);
        *reinterpret_cast<float4*>(yr + seg0 + 4 * m) = v;
    }
}

extern "C" void kernel_launch(void* const* d_in, const int* in_sizes, int n_in,
                              void* d_out, int out_size, void* d_ws, size_t ws_size,
                              hipStream_t stream) {
    const float* x = (const float*)d_in[0];
    float* out = (float*)d_out;
    const int rows = in_sizes[0] / T_LEN;        // 64

    // torchaudio lowpass_biquad coefficients (double -> f32, matches reference)
    const double SR = 22050.0, CUT = 0.4 * SR, Q = 0.707;
    double w0 = 2.0 * M_PI * CUT / SR;
    double alpha = sin(w0) / (2.0 * Q);
    double cosw = cos(w0);
    double a0d = 1.0 + alpha;
    float b0 = (float)((1.0 - cosw) / 2.0 / a0d);
    float b1 = (float)((1.0 - cosw) / a0d);
    float b2 = b0;
    float a1 = (float)(-2.0 * cosw / a0d);
    float a2 = (float)((1.0 - alpha) / a0d);

    const int blocks = rows * BPR;               // 64 * 64 = 4096
    lowpass_kernel<<<blocks, TPB, 0, stream>>>(x, out, b0, b1, b2, a1, a2);
}

// Round 5
// 27.816 us; speedup vs baseline: 1.0910x; 1.0101x over previous
//
#include <hip/hip_runtime.h>
#include <math.h>

// Biquad lowpass over [B, T] f32, T = 262144.
// Overlap-and-discard, direct-global reads + LDS output transpose only:
//  - each thread owns 16 contiguous outputs; reads its 40-float window
//    [16*tid-24, 16*tid+16) directly from global as 10 independent float4
//    loads (deep ILP, no load->compute barrier). Lane windows are 64B apart,
//    overlap 96B -> every line fully covered; 2.5x read overlap absorbed by
//    L1/L2 (same-wave temporal reuse), HBM FETCH stays ~1x.
//  - 24 warm-up + 16 output steps (poles |z|~0.6425 -> 0.6425^24 ~ 2.4e-5
//    init-state error vs 2e-2 threshold)
//  - outputs in regs -> XOR-swizzled LDS (sw(i)=i^(((i>>4)&7)<<2), bijective
//    within 4096, keeps bits[1:0] -> b128 ops; both phases conflict-free,
//    verified 0 SQ_LDS_BANK_CONFLICT in R4) -> ONE barrier -> coalesced
//    float4 stores. LDS = 16 KB, 8 LDS ops/thread, 1 barrier total.
constexpr int T_LEN = 262144;
constexpr int CH    = 16;              // outputs per thread
constexpr int WARM  = 24;              // multiple of 4
constexpr int TPB   = 256;
constexpr int SEG   = TPB * CH;        // 4096 floats per block
constexpr int BPR   = T_LEN / SEG;     // 64 blocks per row
constexpr int NLD   = (CH + WARM) / 4; // 10 float4 loads per thread

__device__ __forceinline__ int sw(int i) { return i ^ (((i >> 4) & 7) << 2); }

__global__ __launch_bounds__(TPB, 6) void lowpass_kernel(
    const float* __restrict__ x, float* __restrict__ out,
    float b0, float b1, float b2, float a1, float a2)
{
    __shared__ float lds[SEG];          // sw() is closed on [0, SEG)
    const int tid = threadIdx.x;
    const size_t rbase = (size_t)(blockIdx.x / BPR) * T_LEN;
    const int seg0 = (blockIdx.x % BPR) * SEG;   // row-local segment start
    const float* __restrict__ xr = x   + rbase;
    float*       __restrict__ yr = out + rbase;

    // ---- direct global loads: thread window [w0, w0+40), 16B-aligned ----
    const int w0 = seg0 + 16 * tid - WARM;
    float4 xv[NLD];
    #pragma unroll
    for (int j = 0; j < NLD; ++j) {
        const int gp = w0 + 4 * j;
        xv[j] = (gp >= 0) ? *reinterpret_cast<const float4*>(xr + gp)
                          : make_float4(0.f, 0.f, 0.f, 0.f);
    }

    // ---- recurrence: 24 warm-up + 16 output steps (all static idx) ----
    float x1 = 0.f, x2 = 0.f, y1 = 0.f, y2 = 0.f;
    auto step = [&](float xc) -> float {
        const float u = fmaf(b0, xc, fmaf(b1, x1, b2 * x2));
        const float y = fmaf(-a1, y1, fmaf(-a2, y2, u));
        x2 = x1; x1 = xc; y2 = y1; y1 = y;
        return y;
    };

    #pragma unroll
    for (int j = 0; j < WARM / 4; ++j) {         // 6 warm-up float4s
        step(xv[j].x); step(xv[j].y); step(xv[j].z); step(xv[j].w);
    }
    float4 ov[CH / 4];
    #pragma unroll
    for (int k = 0; k < CH / 4; ++k) {
        const float4 v = xv[WARM / 4 + k];
        ov[k].x = fminf(fmaxf(step(v.x), -1.f), 1.f);
        ov[k].y = fminf(fmaxf(step(v.y), -1.f), 1.f);
        ov[k].z = fminf(fmaxf(step(v.z), -1.f), 1.f);
        ov[k].w = fminf(fmaxf(step(v.w), -1.f), 1.f);
    }

    // ---- output transpose through LDS (write conflict-free b128) ----
    #pragma unroll
    for (int k = 0; k < CH / 4; ++k)
        *reinterpret_cast<float4*>(&lds[sw(16 * tid + 4 * k)]) = ov[k];
    __syncthreads();

    // ---- coalesced float4 store ----
    #pragma unroll
    for (int j = 0; j < SEG / 4 / TPB; ++j) {    // 4 iters, exact
        const int m = tid + j * TPB;
        const float4 v = *reinterpret_cast<const float4*>(&lds[sw(4 * m)]);
        *reinterpret_cast<float4*>(yr + seg0 + 4 * m) = v;
    }
}

extern "C" void kernel_launch(void* const* d_in, const int* in_sizes, int n_in,
                              void* d_out, int out_size, void* d_ws, size_t ws_size,
                              hipStream_t stream) {
    const float* x = (const float*)d_in[0];
    float* out = (float*)d_out;
    const int rows = in_sizes[0] / T_LEN;        // 64

    // torchaudio lowpass_biquad coefficients (double -> f32, matches reference)
    const double SR = 22050.0, CUT = 0.4 * SR, Q = 0.707;
    double w0 = 2.0 * M_PI * CUT / SR;
    double alpha = sin(w0) / (2.0 * Q);
    double cosw = cos(w0);
    double a0d = 1.0 + alpha;
    float b0 = (float)((1.0 - cosw) / 2.0 / a0d);
    float b1 = (float)((1.0 - cosw) / a0d);
    float b2 = b0;
    float a1 = (float)(-2.0 * cosw / a0d);
    float a2 = (float)((1.0 - alpha) / a0d);

    const int blocks = rows * BPR;               // 64 * 64 = 4096
    lowpass_kernel<<<blocks, TPB, 0, stream>>>(x, out, b0, b1, b2, a1, a2);
}

// Round 6
// 27.639 us; speedup vs baseline: 1.0979x; 1.0064x over previous
//
#include <hip/hip_runtime.h>
#include <math.h>

// Biquad lowpass over [B, T] f32, T = 262144.
// R6 = R4 structure (all-coalesced, all-b128, zero-conflict XOR swizzle)
//      + NONTEMPORAL global loads/stores (streams have no reuse; keep the
//        67 MB dead write stream from thrashing the 4 MiB/XCD L2 against
//        the read stream).
//  - block of 256 threads owns a contiguous 4096-float segment (16/thread)
//  - stage [seg-24, seg+4096) via coalesced nt float4 loads into XOR-swizzled
//    LDS: sw(i) = i ^ (((i>>4)&7)<<2) — bijective, keeps bits[1:0] -> all
//    phases are 16B-aligned b128 ops; measured 0 SQ_LDS_BANK_CONFLICT (R4).
//  - 24 warm-up + 16 output steps per thread (poles |z| ~ 0.6425 ->
//    0.6425^24 ~ 2.4e-5 init-state error vs 2e-2 threshold)
//  - outputs in regs (static unroll) -> LDS transpose -> coalesced nt stores
constexpr int T_LEN = 262144;
constexpr int CH    = 16;              // outputs per thread
constexpr int WARM  = 24;              // multiple of 4
constexpr int TPB   = 256;
constexpr int SEG   = TPB * CH;        // 4096 floats per block
constexpr int LTOT  = SEG + WARM;      // 4120 floats staged
constexpr int LSWZ  = LTOT + 8;        // swizzle headroom
constexpr int BPR   = T_LEN / SEG;     // 64 blocks per row

typedef float f32x4 __attribute__((ext_vector_type(4)));

__device__ __forceinline__ int sw(int i) { return i ^ (((i >> 4) & 7) << 2); }

__global__ __launch_bounds__(TPB, 6) void lowpass_kernel(
    const float* __restrict__ x, float* __restrict__ out,
    float b0, float b1, float b2, float a1, float a2)
{
    __shared__ float lds[LSWZ];
    const int tid = threadIdx.x;
    const size_t rbase = (size_t)(blockIdx.x / BPR) * T_LEN;
    const int seg0 = (blockIdx.x % BPR) * SEG;   // row-local segment start
    const float* __restrict__ xr = x   + rbase;
    float*       __restrict__ yr = out + rbase;

    // ---- stage [seg0-WARM, seg0+SEG) as nt b128; zeros before row start ----
    #pragma unroll
    for (int j = 0; j < (LTOT / 4 + TPB - 1) / TPB; ++j) {   // 5 iters
        const int m = tid + j * TPB;
        if (m < LTOT / 4) {
            const int idx  = 4 * m;              // local staged index
            const int gpos = seg0 - WARM + idx;  // row-local sample index
            f32x4 v = (f32x4)(0.f);
            if (gpos >= 0)
                v = __builtin_nontemporal_load(
                        reinterpret_cast<const f32x4*>(xr + gpos));
            *reinterpret_cast<f32x4*>(&lds[sw(idx)]) = v;
        }
    }
    __syncthreads();

    // ---- recurrence: 24 warm-up + 16 output steps, b128 LDS reads ----
    float x1 = 0.f, x2 = 0.f, y1 = 0.f, y2 = 0.f;
    const int base = 16 * tid;
    auto step = [&](float xc) -> float {
        const float u = fmaf(b0, xc, fmaf(b1, x1, b2 * x2));
        const float y = fmaf(-a1, y1, fmaf(-a2, y2, u));
        x2 = x1; x1 = xc; y2 = y1; y1 = y;
        return y;
    };

    #pragma unroll
    for (int k = 0; k < WARM / 4; ++k) {         // 6 warm-up b128 reads
        const f32x4 v = *reinterpret_cast<const f32x4*>(&lds[sw(base + 4 * k)]);
        step(v.x); step(v.y); step(v.z); step(v.w);
    }
    f32x4 ov[CH / 4];
    #pragma unroll
    for (int k = 0; k < CH / 4; ++k) {           // 4 output b128 reads
        const f32x4 v =
            *reinterpret_cast<const f32x4*>(&lds[sw(base + WARM + 4 * k)]);
        ov[k].x = fminf(fmaxf(step(v.x), -1.f), 1.f);
        ov[k].y = fminf(fmaxf(step(v.y), -1.f), 1.f);
        ov[k].z = fminf(fmaxf(step(v.z), -1.f), 1.f);
        ov[k].w = fminf(fmaxf(step(v.w), -1.f), 1.f);
    }
    __syncthreads();   // all input reads done before overwrite

    // ---- transpose outputs through LDS (conflict-free b128 writes) ----
    #pragma unroll
    for (int k = 0; k < CH / 4; ++k)
        *reinterpret_cast<f32x4*>(&lds[sw(base + 4 * k)]) = ov[k];
    __syncthreads();

    // ---- coalesced nt float4 stores ----
    #pragma unroll
    for (int j = 0; j < SEG / 4 / TPB; ++j) {    // 4 iters, exact
        const int m = tid + j * TPB;
        const f32x4 v = *reinterpret_cast<const f32x4*>(&lds[sw(4 * m)]);
        __builtin_nontemporal_store(v, reinterpret_cast<f32x4*>(yr + seg0 + 4 * m));
    }
}

extern "C" void kernel_launch(void* const* d_in, const int* in_sizes, int n_in,
                              void* d_out, int out_size, void* d_ws, size_t ws_size,
                              hipStream_t stream) {
    const float* x = (const float*)d_in[0];
    float* out = (float*)d_out;
    const int rows = in_sizes[0] / T_LEN;        // 64

    // torchaudio lowpass_biquad coefficients (double -> f32, matches reference)
    const double SR = 22050.0, CUT = 0.4 * SR, Q = 0.707;
    double w0 = 2.0 * M_PI * CUT / SR;
    double alpha = sin(w0) / (2.0 * Q);
    double cosw = cos(w0);
    double a0d = 1.0 + alpha;
    float b0 = (float)((1.0 - cosw) / 2.0 / a0d);
    float b1 = (float)((1.0 - cosw) / a0d);
    float b2 = b0;
    float a1 = (float)(-2.0 * cosw / a0d);
    float a2 = (float)((1.0 - alpha) / a0d);

    const int blocks = rows * BPR;               // 64 * 64 = 4096
    lowpass_kernel<<<blocks, TPB, 0, stream>>>(x, out, b0, b1, b2, a1, a2);
}